// Round 2
// baseline (5097.533 us; speedup 1.0000x reference)
//
#include <hip/hip_runtime.h>
#include <math.h>

#define IN_DIM 1024
#define E_DIM  256
#define N_EXP  512
#define N_TOK  131072   // 64 * 2048
#define TM     32       // tokens per block
#define BK     32       // k-chunk for GEMM1
#define XS_STR 34       // doubles per x-tile LDS row
#define WS_STR 260      // floats per W-tile LDS row
#define PJ_STR 32       // doubles per projn LDS row (no pad; write conflicts negligible)

// ---------------------------------------------------------------------------
// Kernel A: L2-normalize center rows in fp64, write TRANSPOSED: cTd[k][ctr]
// ---------------------------------------------------------------------------
__global__ __launch_bounds__(64) void center_norm_kernel(
    const float* __restrict__ centers, double* __restrict__ cTd)
{
    const int ctr  = blockIdx.x;   // 0..511
    const int lane = threadIdx.x;  // 0..63
    const float* row = centers + (size_t)ctr * E_DIM;
    double v[4];
    double s = 0.0;
#pragma unroll
    for (int i = 0; i < 4; ++i) { v[i] = (double)row[lane + 64 * i]; s = fma(v[i], v[i], s); }
#pragma unroll
    for (int off = 32; off >= 1; off >>= 1) s += __shfl_xor(s, off, 64);
    const double inv = 1.0 / fmax(sqrt(s), 1e-12);
#pragma unroll
    for (int i = 0; i < 4; ++i)
        cTd[(size_t)(lane + 64 * i) * N_EXP + ctr] = v[i] * inv;
}

// ---------------------------------------------------------------------------
// Kernel B: fused fp64-accurate router.
// 256 threads, 32 tokens/block. tx=tid&31, ty=tid>>5 (tokens ty*4..ty*4+3).
// ---------------------------------------------------------------------------
__global__ __launch_bounds__(256) void router_kernel(
    const float* __restrict__ x, const float* __restrict__ W,
    const float* __restrict__ bias, const double* __restrict__ cTd,
    float* __restrict__ out)
{
    __shared__ __align__(16) char smem_raw[65536];   // 64 KB union of all phases
    const int tid = threadIdx.x;
    const int tx  = tid & 31;
    const int ty  = tid >> 5;
    const int tokBase = blockIdx.x * TM;

    double* xs  = (double*)smem_raw;                          // [BK][XS_STR] dbl
    float*  wsm = (float*)(smem_raw + BK * XS_STR * 8);       // [BK][WS_STR] f32

    double acc[4][8];   // [token i][expert j], fp64 accumulators
#pragma unroll
    for (int i = 0; i < 4; ++i)
#pragma unroll
        for (int j = 0; j < 8; ++j) acc[i][j] = 0.0;

    const int lt = tid >> 3;           // staging row 0..31
    const int lk = (tid & 7) * 4;      // staging k 0,4,...,28

    // ---------------- GEMM1 (fp64): proj[t][e] = sum_k x[t][k]*W[e][k] -----
    for (int k0 = 0; k0 < IN_DIM; k0 += BK) {
        {   // x tile: 32 tok x 32 k, transposed, converted to double
            const float4 xv = *(const float4*)(x + (size_t)(tokBase + lt) * IN_DIM + k0 + lk);
            xs[(lk + 0) * XS_STR + lt] = (double)xv.x;
            xs[(lk + 1) * XS_STR + lt] = (double)xv.y;
            xs[(lk + 2) * XS_STR + lt] = (double)xv.z;
            xs[(lk + 3) * XS_STR + lt] = (double)xv.w;
        }
#pragma unroll
        for (int p = 0; p < 8; ++p) {   // W tile: 256 exp x 32 k (fp32, exact)
            const int e = lt + p * 32;
            const float4 wv = *(const float4*)(W + (size_t)e * IN_DIM + k0 + lk);
            wsm[(lk + 0) * WS_STR + e] = wv.x;
            wsm[(lk + 1) * WS_STR + e] = wv.y;
            wsm[(lk + 2) * WS_STR + e] = wv.z;
            wsm[(lk + 3) * WS_STR + e] = wv.w;
        }
        __syncthreads();
#pragma unroll
        for (int kk = 0; kk < BK; ++kk) {
            const double2 a0 = *(const double2*)(xs + kk * XS_STR + ty * 4);
            const double2 a1 = *(const double2*)(xs + kk * XS_STR + ty * 4 + 2);
            const float4 bf0 = *(const float4*)(wsm + kk * WS_STR + tx * 4);
            const float4 bf1 = *(const float4*)(wsm + kk * WS_STR + 128 + tx * 4);
            const double a_[4] = {a0.x, a0.y, a1.x, a1.y};
            const double b_[8] = {(double)bf0.x, (double)bf0.y, (double)bf0.z, (double)bf0.w,
                                  (double)bf1.x, (double)bf1.y, (double)bf1.z, (double)bf1.w};
#pragma unroll
            for (int i = 0; i < 4; ++i)
#pragma unroll
                for (int j = 0; j < 8; ++j)
                    acc[i][j] = fma(a_[i], b_[j], acc[i][j]);
        }
        __syncthreads();
    }

    // ------- bias (fp64) + per-token L2 norm via 32-lane shuffle reduce ----
    const float4 bv0 = *(const float4*)(bias + tx * 4);
    const float4 bv1 = *(const float4*)(bias + 128 + tx * 4);
    const double bb[8] = {(double)bv0.x, (double)bv0.y, (double)bv0.z, (double)bv0.w,
                          (double)bv1.x, (double)bv1.y, (double)bv1.z, (double)bv1.w};
    double pj[4][8];
    double invn[4];
#pragma unroll
    for (int i = 0; i < 4; ++i) {
        double s = 0.0;
#pragma unroll
        for (int j = 0; j < 8; ++j) {
            pj[i][j] = acc[i][j] + bb[j];
            s = fma(pj[i][j], pj[i][j], s);
        }
        // sum across the 32 tx-lanes that share this token (width-32 segments
        // align with ty groups since tid = ty*32 + tx)
#pragma unroll
        for (int off = 16; off >= 1; off >>= 1) s += __shfl_xor(s, off, 32);
        invn[i] = 1.0 / fmax(sqrt(s), 1e-12);
    }

    // write NORMALIZED projn[e][t] (fp64) to LDS  (overwrites GEMM1 tiles;
    // safe: loop ended with __syncthreads and acc is in registers)
    double* projn = (double*)smem_raw;   // [E_DIM][PJ_STR]
#pragma unroll
    for (int j = 0; j < 8; ++j) {
        const int e = (j < 4) ? (tx * 4 + j) : (128 + tx * 4 + (j - 4));
#pragma unroll
        for (int i = 0; i < 4; ++i)
            projn[e * PJ_STR + ty * 4 + i] = pj[i][j] * invn[i];
    }
    __syncthreads();

    // ---------------- GEMM2 (fp64) + fused per-thread top-2 ----------------
    double tv1[4], tv2[4];
    int    ti1[4], ti2[4];
#pragma unroll
    for (int i = 0; i < 4; ++i) { tv1[i] = -1e300; tv2[i] = -1e300; ti1[i] = 0; ti2[i] = 0; }

    for (int g = 0; g < 4; ++g) {        // center groups: c = g*128 + tx*4 + j
        double a2[4][4];
#pragma unroll
        for (int i = 0; i < 4; ++i)
#pragma unroll
            for (int j = 0; j < 4; ++j) a2[i][j] = 0.0;

        const double* cbase = cTd + g * 128 + tx * 4;
        for (int k = 0; k < E_DIM; ++k) {
            const double2 p0 = *(const double2*)(projn + k * PJ_STR + ty * 4);
            const double2 p1 = *(const double2*)(projn + k * PJ_STR + ty * 4 + 2);
            const double2 c0 = *(const double2*)(cbase + (size_t)k * N_EXP);
            const double2 c1 = *(const double2*)(cbase + (size_t)k * N_EXP + 2);
            const double a_[4] = {p0.x, p0.y, p1.x, p1.y};
            const double c_[4] = {c0.x, c0.y, c1.x, c1.y};
#pragma unroll
            for (int i = 0; i < 4; ++i)
#pragma unroll
                for (int j = 0; j < 4; ++j)
                    a2[i][j] = fma(a_[i], c_[j], a2[i][j]);
        }
#pragma unroll
        for (int i = 0; i < 4; ++i)
#pragma unroll
            for (int j = 0; j < 4; ++j) {
                const double v = a2[i][j];
                const int    c = g * 128 + tx * 4 + j;
                if (v > tv1[i] || (v == tv1[i] && c < ti1[i])) {
                    tv2[i] = tv1[i]; ti2[i] = ti1[i]; tv1[i] = v; ti1[i] = c;
                } else if (v > tv2[i] || (v == tv2[i] && c < ti2[i])) {
                    tv2[i] = v; ti2[i] = c;
                }
            }
    }

    // ---------------- merge 32 candidate pairs per token -------------------
    __syncthreads();                       // projn dead; reuse LDS
    double* cand = (double*)smem_raw;      // [32 tok][32 slot][4]
#pragma unroll
    for (int i = 0; i < 4; ++i) {
        const int t = ty * 4 + i;
        double* cd = cand + ((t * 32 + tx) << 2);
        cd[0] = tv1[i]; cd[1] = (double)ti1[i];
        cd[2] = tv2[i]; cd[3] = (double)ti2[i];
    }
    __syncthreads();

    if (tid < 32) {
        double v1 = -1e300, v2 = -1e300;
        int    i1 = 0, i2 = 0;
        for (int s = 0; s < 32; ++s) {
            const double* cd = cand + ((tid * 32 + s) << 2);
            {
                const double v = cd[0]; const int c = (int)cd[1];
                if (v > v1 || (v == v1 && c < i1)) { v2 = v1; i2 = i1; v1 = v; i1 = c; }
                else if (v > v2 || (v == v2 && c < i2)) { v2 = v; i2 = c; }
            }
            {
                const double v = cd[2]; const int c = (int)cd[3];
                if (v > v1 || (v == v1 && c < i1)) { v2 = v1; i2 = i1; v1 = v; i1 = c; }
                else if (v > v2 || (v == v2 && c < i2)) { v2 = v; i2 = c; }
            }
        }
        const double e  = exp(v2 - v1);    // <= 1
        const double dn = 1.0 + e;
        const size_t g  = (size_t)tokBase + tid;
        out[g * 2 + 0] = (float)(1.0 / dn);
        out[g * 2 + 1] = (float)(e / dn);
        out[(size_t)2 * N_TOK + g * 2 + 0] = (float)i1;
        out[(size_t)2 * N_TOK + g * 2 + 1] = (float)i2;
    }
}

// ---------------------------------------------------------------------------
extern "C" void kernel_launch(void* const* d_in, const int* in_sizes, int n_in,
                              void* d_out, int out_size, void* d_ws, size_t ws_size,
                              hipStream_t stream)
{
    const float* x       = (const float*)d_in[0];
    const float* W       = (const float*)d_in[1];
    const float* bias    = (const float*)d_in[2];
    const float* centers = (const float*)d_in[3];
    // d_in[4] = top_k (always 2, hard-coded)
    double* cTd = (double*)d_ws;   // 256 x 512 doubles = 1 MB scratch
    float*  out = (float*)d_out;

    center_norm_kernel<<<N_EXP, 64, 0, stream>>>(centers, cTd);
    router_kernel<<<N_TOK / TM, 256, 0, stream>>>(x, W, bias, cTd, out);
}